// Round 7
// baseline (2389.846 us; speedup 1.0000x reference)
//
#include <hip/hip_runtime.h>
#include <cstdint>
#include <cstddef>

#define NN 5000     // nodes per batch block
#define EE 40000    // edges per batch block
#define BATCH 8
#define SS 12
#define FF 16
#define HH 128
#define TOTAL 40000 // BATCH*NN
#define CC 4

// Layout note: ALL per-row state arrays (xt, h0, h1, rh, ub, GR, GU, Cpre) use
// row = bb*NN + n  (batch-major). A per-batch slice is contiguous -> no L2 set
// aliasing, so the per-XCD L2 can actually hold the gather working set.

typedef __attribute__((ext_vector_type(8))) short short8;   // 8 bf16 (4 VGPRs)
typedef __attribute__((ext_vector_type(4))) float f32x4;    // 4 fp32

__device__ __forceinline__ unsigned short f2bf(float f) {
  union { float f; unsigned u; } v; v.f = f;
  unsigned r = v.u + 0x7fff + ((v.u >> 16) & 1);  // RTNE
  return (unsigned short)(r >> 16);
}
__device__ __forceinline__ float bf2f(unsigned short b) {
  union { unsigned u; float f; } v; v.u = ((unsigned)b) << 16;
  return v.f;
}
__device__ __forceinline__ float bflo(unsigned v) {
  union { unsigned u; float f; } x; x.u = v << 16; return x.f;
}
__device__ __forceinline__ float bfhi(unsigned v) {
  union { unsigned u; float f; } x; x.u = v & 0xffff0000u; return x.f;
}

// ---------------- graph preprocessing (once per launch) ----------------

__global__ void deg_cnt_kernel(const int* __restrict__ ei, const float* __restrict__ ew,
                               float* __restrict__ deg, int* __restrict__ cnt) {
  int e = blockIdx.x * 256 + threadIdx.x;
  if (e < EE) {
    int col = ei[EE + e];
    atomicAdd(&deg[col], ew[e]);
    atomicAdd(&cnt[col], 1);
  }
}

__global__ void dis_kernel(const float* __restrict__ deg, float* __restrict__ dis) {
  int n = blockIdx.x * 256 + threadIdx.x;
  if (n < NN) dis[n] = rsqrtf(deg[n] + 1.0f);  // +1: self-loop weight
}

__global__ void scan_kernel(const int* __restrict__ cnt, int* __restrict__ offs) {
  __shared__ int part[256];
  const int CH = (NN + 255) / 256; // 20
  int tid = threadIdx.x;
  int base = tid * CH;
  int s = 0;
  for (int i = 0; i < CH; i++) { int idx = base + i; if (idx < NN) s += cnt[idx]; }
  part[tid] = s;
  __syncthreads();
  for (int off = 1; off < 256; off <<= 1) {
    int v = (tid >= off) ? part[tid - off] : 0;
    __syncthreads();
    part[tid] += v;
    __syncthreads();
  }
  int run = (tid == 0) ? 0 : part[tid - 1];
  for (int i = 0; i < CH; i++) {
    int idx = base + i;
    if (idx < NN) { offs[idx] = run; run += cnt[idx]; }
  }
  if (tid == 255) offs[NN] = run;
}

__global__ void fill_csr_kernel(const int* __restrict__ ei, const float* __restrict__ ew,
                                const float* __restrict__ dis, const int* __restrict__ offs,
                                int* __restrict__ cursor, int* __restrict__ csr_src,
                                float* __restrict__ csr_w) {
  int e = blockIdx.x * 256 + threadIdx.x;
  if (e < EE) {
    int row = ei[e], col = ei[EE + e];
    int pos = offs[col] + atomicAdd(&cursor[col], 1);
    csr_src[pos] = row;
    csr_w[pos] = dis[row] * ew[e] * dis[col];
  }
}

// ---------------- weight prepack: fp32 [k][n] -> bf16 MFMA b-frag order ----------------

__global__ void prepack_kernel(const float* __restrict__ convW, unsigned short* __restrict__ Wp) {
  int idx = blockIdx.x * 256 + threadIdx.x;  // 6*8*8*64 = 24576
  int lane = idx & 63;
  int ks = (idx >> 6) & 7;
  int nt = (idx >> 9) & 7;
  int g = idx >> 12;
  const float* W = convW + (size_t)g * 256 * 128;
  int n = nt * 16 + (lane & 15);
  int k0 = ks * 32 + (lane >> 4) * 8;
  unsigned short v[8];
#pragma unroll
  for (int j = 0; j < 8; j++) v[j] = f2bf(W[(size_t)(k0 + j) * 128 + n]);
  *(uint4*)(Wp + (size_t)idx * 8) = *(const uint4*)v;
}

// ---------------- lin_in: xt = relu(x_t @ Win + bin), bf16, row = bb*NN+n ----------------
// grid (NN*32/256, 8), blockIdx.y = bb.

__global__ __launch_bounds__(256) void lin_in_kernel(const float* __restrict__ x_seq,
                                                     const float* __restrict__ W,
                                                     const float* __restrict__ b,
                                                     unsigned short* __restrict__ xt, int t) {
  int bb = blockIdx.y;
  int idx = blockIdx.x * 256 + threadIdx.x;   // over NN*32
  int n = idx >> 5, fq = idx & 31;            // feats 4fq..4fq+3
  const float* xp = x_seq + (((size_t)bb * SS + t) * NN + n) * FF;
  float4 a = *(const float4*)&b[fq * 4];
#pragma unroll
  for (int ff = 0; ff < FF; ff++) {
    float xv = xp[ff];
    float4 w = *(const float4*)&W[ff * HH + fq * 4];
    a.x += xv * w.x; a.y += xv * w.y; a.z += xv * w.z; a.w += xv * w.w;
  }
  uint2 o;
  o.x = (unsigned)f2bf(fmaxf(a.x, 0.f)) | ((unsigned)f2bf(fmaxf(a.y, 0.f)) << 16);
  o.y = (unsigned)f2bf(fmaxf(a.z, 0.f)) | ((unsigned)f2bf(fmaxf(a.w, 0.f)) << 16);
  *(uint2*)&xt[((size_t)bb * NN + n) * 128 + fq * 4] = o;
}

// ---------------- bf16 MFMA GEMM, LDS-staged vectorized epilogue ----------------

template <int NTW>
__global__ __launch_bounds__(256) void gemm_mfma(const unsigned short* __restrict__ A1,
                                                 const unsigned short* __restrict__ A2,
                                                 const unsigned short* __restrict__ Wp,
                                                 unsigned short* __restrict__ outR,
                                                 unsigned short* __restrict__ outU) {
  __shared__ unsigned short As[64 * 264];  // staging for A (and reused for C epilogue)
  int rowBase = blockIdx.x * 64;
  int tid = threadIdx.x;
  for (int c = tid; c < 2048; c += 256) {
    int row = c >> 5; int rest = c & 31; int half = rest >> 4; int sub = rest & 15;
    const unsigned short* src = (half ? A2 : A1) + ((size_t)(rowBase + row) * 128 + sub * 8);
    *(uint4*)&As[row * 264 + half * 128 + sub * 8] = *(const uint4*)src;
  }
  __syncthreads();
  int wv = tid >> 6, lane = tid & 63;
  int m = lane & 15, q = lane >> 4;
  f32x4 acc[4][NTW];
#pragma unroll
  for (int i = 0; i < 4; i++)
#pragma unroll
    for (int j = 0; j < NTW; j++) acc[i][j] = (f32x4)(0.0f);
  const unsigned short* wbase = Wp + ((size_t)(wv * NTW) * 8 * 64 + lane) * 8;
#pragma unroll
  for (int ks = 0; ks < 8; ks++) {
    short8 a[4];
#pragma unroll
    for (int mt = 0; mt < 4; mt++)
      a[mt] = *(const short8*)&As[(mt * 16 + m) * 264 + ks * 32 + q * 8];
#pragma unroll
    for (int nt = 0; nt < NTW; nt++) {
      short8 b = *(const short8*)(wbase + (size_t)(nt * 8 + ks) * 64 * 8);
#pragma unroll
      for (int mt = 0; mt < 4; mt++)
        acc[mt][nt] = __builtin_amdgcn_mfma_f32_16x16x32_bf16(a[mt], b, acc[mt][nt], 0, 0, 0);
    }
  }
  // epilogue: bf16 C tile -> LDS (padded stride) -> 16B coalesced global stores
  constexpr int NC = NTW * 64;    // 256 (gates) or 128 (candidate)
  constexpr int CST = NC + 8;     // LDS row stride in shorts
  __syncthreads();                // done reading As
#pragma unroll
  for (int mt = 0; mt < 4; mt++)
#pragma unroll
    for (int nt = 0; nt < NTW; nt++) {
      int col = (wv * NTW + nt) * 16 + m;
#pragma unroll
      for (int i = 0; i < 4; i++)
        As[(mt * 16 + q * 4 + i) * CST + col] = f2bf(acc[mt][nt][i]);
    }
  __syncthreads();
  constexpr int CPR = NC / 8;     // 16B chunks per row
  for (int c = tid; c < 64 * CPR; c += 256) {
    int row = c / CPR, cc = c % CPR;
    uint4 v = *(const uint4*)&As[row * CST + cc * 8];
    int col = cc * 8;
    unsigned short* op = (col < 128) ? outR : outU;
    *(uint4*)&op[(size_t)(rowBase + row) * 128 + (col & 127)] = v;
  }
}

// ---------------- gates aggregation: batch-major contiguous slices ----------------
// grid (NN/4, 8), blockIdx.y = bb. Wave = one node; lanes 0-31 gather the full GR
// row (256 B), lanes 32-63 the GU row. Per-batch slice = contiguous 1.28 MB each.

__global__ __launch_bounds__(256) void scatter_gates_kernel(
    const unsigned short* __restrict__ GR, const unsigned short* __restrict__ GU,
    const int* __restrict__ offs, const int* __restrict__ csr_src,
    const float* __restrict__ csr_w, const float* __restrict__ dis,
    const float* __restrict__ bRU, const unsigned short* __restrict__ h,
    unsigned short* __restrict__ rh, unsigned short* __restrict__ u) {
  int bb = blockIdx.y;
  int tid = threadIdx.x;
  int wv = tid >> 6, lane = tid & 63;
  int half = lane >> 5;
  int col = (lane & 31) << 2;
  int n = blockIdx.x * 4 + wv;
  const unsigned short* G = (half ? GU : GR) + (size_t)bb * NN * 128;
  const float* bias = bRU + half * 128 + col;
  float b0 = bias[0], b1 = bias[1], b2 = bias[2], b3 = bias[3];
  float sn = dis[n]; sn *= sn;
  size_t rowSelf = (size_t)bb * NN + n;
  uint2 gv = *(const uint2*)&G[(size_t)n * 128 + col];
  float a0 = sn * bflo(gv.x), a1 = sn * bfhi(gv.x);
  float a2 = sn * bflo(gv.y), a3 = sn * bfhi(gv.y);
  int e0 = offs[n], e1 = offs[n + 1];
  int e = e0;
  for (; e + 1 < e1; e += 2) {
    int s0 = csr_src[e], s1 = csr_src[e + 1];
    float w0 = csr_w[e], w1 = csr_w[e + 1];
    uint2 ga = *(const uint2*)&G[(size_t)s0 * 128 + col];
    uint2 gb = *(const uint2*)&G[(size_t)s1 * 128 + col];
    a0 += w0 * bflo(ga.x); a1 += w0 * bfhi(ga.x);
    a2 += w0 * bflo(ga.y); a3 += w0 * bfhi(ga.y);
    a0 += w1 * bflo(gb.x); a1 += w1 * bfhi(gb.x);
    a2 += w1 * bflo(gb.y); a3 += w1 * bfhi(gb.y);
  }
  if (e < e1) {
    int s0 = csr_src[e];
    float w0 = csr_w[e];
    uint2 ga = *(const uint2*)&G[(size_t)s0 * 128 + col];
    a0 += w0 * bflo(ga.x); a1 += w0 * bfhi(ga.x);
    a2 += w0 * bflo(ga.y); a3 += w0 * bfhi(ga.y);
  }
  float v0 = 1.0f / (1.0f + __expf(-(a0 + b0)));
  float v1 = 1.0f / (1.0f + __expf(-(a1 + b1)));
  float v2 = 1.0f / (1.0f + __expf(-(a2 + b2)));
  float v3 = 1.0f / (1.0f + __expf(-(a3 + b3)));
  if (half == 0) {
    unsigned long long hv = __builtin_nontemporal_load(
        (const unsigned long long*)&h[rowSelf * 128 + col]);
    v0 *= bflo((unsigned)hv); v1 *= bfhi((unsigned)hv);
    v2 *= bflo((unsigned)(hv >> 32)); v3 *= bfhi((unsigned)(hv >> 32));
    unsigned lo = (unsigned)f2bf(v0) | ((unsigned)f2bf(v1) << 16);
    unsigned hi = (unsigned)f2bf(v2) | ((unsigned)f2bf(v3) << 16);
    *(unsigned long long*)&rh[rowSelf * 128 + col] = ((unsigned long long)hi << 32) | lo;
  } else {
    unsigned lo = (unsigned)f2bf(v0) | ((unsigned)f2bf(v1) << 16);
    unsigned hi = (unsigned)f2bf(v2) | ((unsigned)f2bf(v3) << 16);
    __builtin_nontemporal_store(((unsigned long long)hi << 32) | lo,
                                (unsigned long long*)&u[rowSelf * 128 + col]);
  }
}

// ---------------- candidate aggregation + GRU update: batch-major slices ----------------
// grid (NN/8, 8), blockIdx.y = bb. Wave = 2 nodes x 32 lanes. Slice = 1.28 MB.

__global__ __launch_bounds__(256) void scatter_c_update_kernel(
    const unsigned short* __restrict__ Cpre, const int* __restrict__ offs,
    const int* __restrict__ csr_src, const float* __restrict__ csr_w,
    const float* __restrict__ dis, const float* __restrict__ bC,
    const unsigned short* __restrict__ u, unsigned short* __restrict__ h) {
  int bb = blockIdx.y;
  int tid = threadIdx.x;
  int wv = tid >> 6, lane = tid & 63;
  int nh = lane >> 5;             // node-in-pair
  int col = (lane & 31) << 2;
  int n = blockIdx.x * 8 + wv * 2 + nh;
  const unsigned short* Cp = Cpre + (size_t)bb * NN * 128;
  const float* bp = bC + col;
  float b0 = bp[0], b1 = bp[1], b2 = bp[2], b3 = bp[3];
  float sn = dis[n]; sn *= sn;
  size_t rowSelf = (size_t)bb * NN + n;
  uint2 gv = *(const uint2*)&Cp[(size_t)n * 128 + col];
  float a0 = sn * bflo(gv.x), a1 = sn * bfhi(gv.x);
  float a2 = sn * bflo(gv.y), a3 = sn * bfhi(gv.y);
  int e0 = offs[n], e1 = offs[n + 1];
  int e = e0;
  for (; e + 1 < e1; e += 2) {
    int s0 = csr_src[e], s1 = csr_src[e + 1];
    float w0 = csr_w[e], w1 = csr_w[e + 1];
    uint2 ga = *(const uint2*)&Cp[(size_t)s0 * 128 + col];
    uint2 gb = *(const uint2*)&Cp[(size_t)s1 * 128 + col];
    a0 += w0 * bflo(ga.x); a1 += w0 * bfhi(ga.x);
    a2 += w0 * bflo(ga.y); a3 += w0 * bfhi(ga.y);
    a0 += w1 * bflo(gb.x); a1 += w1 * bfhi(gb.x);
    a2 += w1 * bflo(gb.y); a3 += w1 * bfhi(gb.y);
  }
  if (e < e1) {
    int s0 = csr_src[e];
    float w0 = csr_w[e];
    uint2 ga = *(const uint2*)&Cp[(size_t)s0 * 128 + col];
    a0 += w0 * bflo(ga.x); a1 += w0 * bfhi(ga.x);
    a2 += w0 * bflo(ga.y); a3 += w0 * bfhi(ga.y);
  }
  float c0 = 1.0f - 2.0f / (__expf(2.0f * (a0 + b0)) + 1.0f);
  float c1 = 1.0f - 2.0f / (__expf(2.0f * (a1 + b1)) + 1.0f);
  float c2 = 1.0f - 2.0f / (__expf(2.0f * (a2 + b2)) + 1.0f);
  float c3 = 1.0f - 2.0f / (__expf(2.0f * (a3 + b3)) + 1.0f);
  unsigned long long uvp = __builtin_nontemporal_load(
      (const unsigned long long*)&u[rowSelf * 128 + col]);
  unsigned long long hvp = __builtin_nontemporal_load(
      (const unsigned long long*)&h[rowSelf * 128 + col]);
  float u0 = bflo((unsigned)uvp), u1 = bfhi((unsigned)uvp);
  float u2 = bflo((unsigned)(uvp >> 32)), u3 = bfhi((unsigned)(uvp >> 32));
  float h0 = bflo((unsigned)hvp), h1 = bfhi((unsigned)hvp);
  float h2 = bflo((unsigned)(hvp >> 32)), h3 = bfhi((unsigned)(hvp >> 32));
  float n0 = u0 * h0 + (1.0f - u0) * c0;
  float n1 = u1 * h1 + (1.0f - u1) * c1;
  float n2 = u2 * h2 + (1.0f - u2) * c2;
  float n3 = u3 * h3 + (1.0f - u3) * c3;
  unsigned lo = (unsigned)f2bf(n0) | ((unsigned)f2bf(n1) << 16);
  unsigned hi = (unsigned)f2bf(n2) | ((unsigned)f2bf(n3) << 16);
  __builtin_nontemporal_store(((unsigned long long)hi << 32) | lo,
                              (unsigned long long*)&h[rowSelf * 128 + col]);
}

// ---------------- BatchNorm stats ----------------

__global__ __launch_bounds__(256) void bn_stats_kernel(const unsigned short* __restrict__ h,
                                                       float* __restrict__ sums) {
  __shared__ float ls[512];
  int tid = threadIdx.x;
  float s = 0.f, sq = 0.f;
  for (size_t idx = (size_t)blockIdx.x * 256 + tid; idx < (size_t)TOTAL * HH;
       idx += (size_t)gridDim.x * 256) {
    float v = bf2f(h[idx]);
    s += v; sq += v * v;
  }
  ls[tid] = s; ls[256 + tid] = sq;
  __syncthreads();
  if (tid < 128) {
    atomicAdd(&sums[tid], ls[tid] + ls[tid + 128]);
    atomicAdd(&sums[128 + tid], ls[256 + tid] + ls[256 + tid + 128]);
  }
}

// ---------------- fused BN -> relu -> lin_out -> log_softmax ----------------

__global__ __launch_bounds__(256) void final_kernel(const unsigned short* __restrict__ h,
                                                    const float* __restrict__ sums,
                                                    const float* __restrict__ gamma,
                                                    const float* __restrict__ beta,
                                                    const float* __restrict__ Wout,
                                                    const float* __restrict__ bout,
                                                    float* __restrict__ out) {
  int wid = threadIdx.x >> 6, lane = threadIdx.x & 63;
  int row = blockIdx.x * 4 + wid; // row = bb*NN+n == reference row order
  if (row >= TOTAL) return;
  const float inv = 1.0f / (float)TOTAL;
  float p0 = 0.f, p1 = 0.f, p2 = 0.f, p3 = 0.f;
#pragma unroll
  for (int jj = 0; jj < 2; jj++) {
    int j = lane + jj * 64;
    float mean = sums[j] * inv;
    float var = sums[128 + j] * inv - mean * mean;
    float hn = (bf2f(h[(size_t)row * HH + j]) - mean) * rsqrtf(var + 1e-5f) * gamma[j] + beta[j];
    hn = fmaxf(hn, 0.0f);
    p0 += hn * Wout[j * 4 + 0];
    p1 += hn * Wout[j * 4 + 1];
    p2 += hn * Wout[j * 4 + 2];
    p3 += hn * Wout[j * 4 + 3];
  }
  for (int off = 32; off; off >>= 1) {
    p0 += __shfl_down(p0, off);
    p1 += __shfl_down(p1, off);
    p2 += __shfl_down(p2, off);
    p3 += __shfl_down(p3, off);
  }
  if (lane == 0) {
    p0 += bout[0]; p1 += bout[1]; p2 += bout[2]; p3 += bout[3];
    float m = fmaxf(fmaxf(p0, p1), fmaxf(p2, p3));
    float e = __expf(p0 - m) + __expf(p1 - m) + __expf(p2 - m) + __expf(p3 - m);
    float lse = m + __logf(e);
    float* o = out + (size_t)row * 4;
    o[0] = p0 - lse; o[1] = p1 - lse; o[2] = p2 - lse; o[3] = p3 - lse;
  }
}

// ---------------- launcher ----------------

extern "C" void kernel_launch(void* const* d_in, const int* in_sizes, int n_in,
                              void* d_out, int out_size, void* d_ws, size_t ws_size,
                              hipStream_t stream) {
  const float* x_seq = (const float*)d_in[0];
  const int* ei      = (const int*)d_in[1];
  const float* ew    = (const float*)d_in[2];
  const float* Win   = (const float*)d_in[3];
  const float* bin   = (const float*)d_in[4];
  const float* convW = (const float*)d_in[5];
  const float* convB = (const float*)d_in[6];
  const float* gamma = (const float*)d_in[7];
  const float* beta  = (const float*)d_in[8];
  const float* Wout  = (const float*)d_in[9];
  const float* bout  = (const float*)d_in[10];
  float* out = (float*)d_out;

  char* ws = (char*)d_ws;
  size_t off = 0;
  auto alloc = [&](size_t bytes) {
    void* p = ws + off;
    off += (bytes + 1023) & ~(size_t)1023;
    return p;
  };
  float* deg     = (float*)alloc(NN * 4);
  float* dis     = (float*)alloc(NN * 4);
  int*   cnt     = (int*)alloc(NN * 4);
  int*   offs    = (int*)alloc((NN + 1) * 4);
  int*   cursor  = (int*)alloc(NN * 4);
  int*   csr_src = (int*)alloc(EE * 4);
  float* csr_w   = (float*)alloc(EE * 4);
  float* sums    = (float*)alloc(256 * 4);
  unsigned short* Wp = (unsigned short*)alloc(6 * 32768 * 2);  // packed conv weights
  const size_t NH = (size_t)TOTAL * HH; // 5,120,000
  unsigned short* h0 = (unsigned short*)alloc(NH * 2);
  unsigned short* h1 = (unsigned short*)alloc(NH * 2);
  unsigned short* xt = (unsigned short*)alloc(NH * 2);
  unsigned short* rh = (unsigned short*)alloc(NH * 2);
  unsigned short* ub = (unsigned short*)alloc(NH * 2);
  unsigned short* GR = (unsigned short*)alloc(NH * 2);
  unsigned short* GU = (unsigned short*)alloc(NH * 2);
  unsigned short* Cpre = GR;  // candidate pre-scatter reuses GR

  hipMemsetAsync(deg, 0, NN * 4, stream);
  hipMemsetAsync(cnt, 0, NN * 4, stream);
  hipMemsetAsync(cursor, 0, NN * 4, stream);
  hipMemsetAsync(sums, 0, 256 * 4, stream);
  hipMemsetAsync(h0, 0, NH * 2, stream);
  hipMemsetAsync(h1, 0, NH * 2, stream);

  deg_cnt_kernel<<<(EE + 255) / 256, 256, 0, stream>>>(ei, ew, deg, cnt);
  dis_kernel<<<(NN + 255) / 256, 256, 0, stream>>>(deg, dis);
  scan_kernel<<<1, 256, 0, stream>>>(cnt, offs);
  fill_csr_kernel<<<(EE + 255) / 256, 256, 0, stream>>>(ei, ew, dis, offs, cursor, csr_src, csr_w);
  prepack_kernel<<<24576 / 256, 256, 0, stream>>>(convW, Wp);

  for (int t = 0; t < SS; t++) {
    lin_in_kernel<<<dim3(NN * 32 / 256, 8), 256, 0, stream>>>(x_seq, Win, bin, xt, t);
    for (int l = 0; l < 2; l++) {
      const unsigned short* xin = (l == 0) ? xt : h0;
      unsigned short* h = (l == 0) ? h0 : h1;
      const unsigned short* Wg = Wp + (size_t)(l * 3) * 32768;
      const unsigned short* Wc = Wp + (size_t)(l * 3 + 2) * 32768;
      const float* bRU = convB + (size_t)l * 3 * HH;
      const float* bC  = bRU + 2 * HH;
      gemm_mfma<4><<<TOTAL / 64, 256, 0, stream>>>(xin, h, Wg, GR, GU);
      scatter_gates_kernel<<<dim3(NN / 4, 8), 256, 0, stream>>>(GR, GU, offs, csr_src, csr_w,
                                                                dis, bRU, h, rh, ub);
      gemm_mfma<2><<<TOTAL / 64, 256, 0, stream>>>(xin, rh, Wc, Cpre, Cpre);
      scatter_c_update_kernel<<<dim3(NN / 8, 8), 256, 0, stream>>>(Cpre, offs, csr_src, csr_w,
                                                                   dis, bC, ub, h);
    }
  }

  bn_stats_kernel<<<256, 256, 0, stream>>>(h1, sums);
  final_kernel<<<TOTAL / 4, 256, 0, stream>>>(h1, sums, gamma, beta, Wout, bout, out);
}

// Round 8
// 2077.969 us; speedup vs baseline: 1.1501x; 1.1501x over previous
//
#include <hip/hip_runtime.h>
#include <cstdint>
#include <cstddef>

#define NN 5000     // nodes per batch block
#define EE 40000    // edges per batch block
#define BATCH 8
#define SS 12
#define FF 16
#define HH 128
#define TOTAL 40000 // BATCH*NN
#define CC 4

// Layout: per-row state arrays use row = n*8 + bb (batch-interleaved) so one
// edge's gather touches 8 consecutive rows = 2KB contiguous (r3 structure,
// best measured). Gathers use 16B/lane uint4 loads (2 waves per node).

typedef __attribute__((ext_vector_type(8))) short short8;   // 8 bf16 (4 VGPRs)
typedef __attribute__((ext_vector_type(4))) float f32x4;    // 4 fp32

__device__ __forceinline__ unsigned short f2bf(float f) {
  union { float f; unsigned u; } v; v.f = f;
  unsigned r = v.u + 0x7fff + ((v.u >> 16) & 1);  // RTNE
  return (unsigned short)(r >> 16);
}
__device__ __forceinline__ float bf2f(unsigned short b) {
  union { unsigned u; float f; } v; v.u = ((unsigned)b) << 16;
  return v.f;
}
__device__ __forceinline__ float bflo(unsigned v) {
  union { unsigned u; float f; } x; x.u = v << 16; return x.f;
}
__device__ __forceinline__ float bfhi(unsigned v) {
  union { unsigned u; float f; } x; x.u = v & 0xffff0000u; return x.f;
}

// ---------------- graph preprocessing (once per launch) ----------------

__global__ void deg_cnt_kernel(const int* __restrict__ ei, const float* __restrict__ ew,
                               float* __restrict__ deg, int* __restrict__ cnt) {
  int e = blockIdx.x * 256 + threadIdx.x;
  if (e < EE) {
    int col = ei[EE + e];
    atomicAdd(&deg[col], ew[e]);
    atomicAdd(&cnt[col], 1);
  }
}

__global__ void dis_kernel(const float* __restrict__ deg, float* __restrict__ dis) {
  int n = blockIdx.x * 256 + threadIdx.x;
  if (n < NN) dis[n] = rsqrtf(deg[n] + 1.0f);  // +1: self-loop weight
}

__global__ void scan_kernel(const int* __restrict__ cnt, int* __restrict__ offs) {
  __shared__ int part[256];
  const int CH = (NN + 255) / 256; // 20
  int tid = threadIdx.x;
  int base = tid * CH;
  int s = 0;
  for (int i = 0; i < CH; i++) { int idx = base + i; if (idx < NN) s += cnt[idx]; }
  part[tid] = s;
  __syncthreads();
  for (int off = 1; off < 256; off <<= 1) {
    int v = (tid >= off) ? part[tid - off] : 0;
    __syncthreads();
    part[tid] += v;
    __syncthreads();
  }
  int run = (tid == 0) ? 0 : part[tid - 1];
  for (int i = 0; i < CH; i++) {
    int idx = base + i;
    if (idx < NN) { offs[idx] = run; run += cnt[idx]; }
  }
  if (tid == 255) offs[NN] = run;
}

__global__ void fill_csr_kernel(const int* __restrict__ ei, const float* __restrict__ ew,
                                const float* __restrict__ dis, const int* __restrict__ offs,
                                int* __restrict__ cursor, int* __restrict__ csr_src,
                                float* __restrict__ csr_w) {
  int e = blockIdx.x * 256 + threadIdx.x;
  if (e < EE) {
    int row = ei[e], col = ei[EE + e];
    int pos = offs[col] + atomicAdd(&cursor[col], 1);
    csr_src[pos] = row;
    csr_w[pos] = dis[row] * ew[e] * dis[col];
  }
}

// ---------------- weight prepack: fp32 [k][n] -> bf16 MFMA b-frag order ----------------

__global__ void prepack_kernel(const float* __restrict__ convW, unsigned short* __restrict__ Wp) {
  int idx = blockIdx.x * 256 + threadIdx.x;  // 6*8*8*64 = 24576
  int lane = idx & 63;
  int ks = (idx >> 6) & 7;
  int nt = (idx >> 9) & 7;
  int g = idx >> 12;
  const float* W = convW + (size_t)g * 256 * 128;
  int n = nt * 16 + (lane & 15);
  int k0 = ks * 32 + (lane >> 4) * 8;
  unsigned short v[8];
#pragma unroll
  for (int j = 0; j < 8; j++) v[j] = f2bf(W[(size_t)(k0 + j) * 128 + n]);
  *(uint4*)(Wp + (size_t)idx * 8) = *(const uint4*)v;
}

// ---------------- lin_in: xt = relu(x_t @ Win + bin), bf16 out, row = n*8+bb ----------------

__global__ __launch_bounds__(256) void lin_in_kernel(const float* __restrict__ x_seq,
                                                     const float* __restrict__ W,
                                                     const float* __restrict__ b,
                                                     unsigned short* __restrict__ xt, int t) {
  int idx = blockIdx.x * 256 + threadIdx.x;   // over TOTAL*16
  int row = idx >> 4, fh = idx & 15;          // feats 8fh..8fh+7
  int n = row >> 3, bb = row & 7;
  const float* xp = x_seq + (((size_t)bb * SS + t) * NN + n) * FF;
  float4 a0 = *(const float4*)&b[fh * 8];
  float4 a1 = *(const float4*)&b[fh * 8 + 4];
#pragma unroll
  for (int ff = 0; ff < FF; ff++) {
    float xv = xp[ff];
    float4 w0 = *(const float4*)&W[ff * HH + fh * 8];
    float4 w1 = *(const float4*)&W[ff * HH + fh * 8 + 4];
    a0.x += xv * w0.x; a0.y += xv * w0.y; a0.z += xv * w0.z; a0.w += xv * w0.w;
    a1.x += xv * w1.x; a1.y += xv * w1.y; a1.z += xv * w1.z; a1.w += xv * w1.w;
  }
  uint4 o;
  o.x = (unsigned)f2bf(fmaxf(a0.x, 0.f)) | ((unsigned)f2bf(fmaxf(a0.y, 0.f)) << 16);
  o.y = (unsigned)f2bf(fmaxf(a0.z, 0.f)) | ((unsigned)f2bf(fmaxf(a0.w, 0.f)) << 16);
  o.z = (unsigned)f2bf(fmaxf(a1.x, 0.f)) | ((unsigned)f2bf(fmaxf(a1.y, 0.f)) << 16);
  o.w = (unsigned)f2bf(fmaxf(a1.z, 0.f)) | ((unsigned)f2bf(fmaxf(a1.w, 0.f)) << 16);
  *(uint4*)&xt[(size_t)row * 128 + fh * 8] = o;
}

// ---------------- bf16 MFMA GEMM, LDS-staged vectorized epilogue ----------------

template <int NTW>
__global__ __launch_bounds__(256) void gemm_mfma(const unsigned short* __restrict__ A1,
                                                 const unsigned short* __restrict__ A2,
                                                 const unsigned short* __restrict__ Wp,
                                                 unsigned short* __restrict__ outR,
                                                 unsigned short* __restrict__ outU) {
  __shared__ unsigned short As[64 * 264];  // A staging; reused for C epilogue
  int rowBase = blockIdx.x * 64;
  int tid = threadIdx.x;
  for (int c = tid; c < 2048; c += 256) {
    int row = c >> 5; int rest = c & 31; int half = rest >> 4; int sub = rest & 15;
    const unsigned short* src = (half ? A2 : A1) + ((size_t)(rowBase + row) * 128 + sub * 8);
    *(uint4*)&As[row * 264 + half * 128 + sub * 8] = *(const uint4*)src;
  }
  __syncthreads();
  int wv = tid >> 6, lane = tid & 63;
  int m = lane & 15, q = lane >> 4;
  f32x4 acc[4][NTW];
#pragma unroll
  for (int i = 0; i < 4; i++)
#pragma unroll
    for (int j = 0; j < NTW; j++) acc[i][j] = (f32x4)(0.0f);
  const unsigned short* wbase = Wp + ((size_t)(wv * NTW) * 8 * 64 + lane) * 8;
#pragma unroll
  for (int ks = 0; ks < 8; ks++) {
    short8 a[4];
#pragma unroll
    for (int mt = 0; mt < 4; mt++)
      a[mt] = *(const short8*)&As[(mt * 16 + m) * 264 + ks * 32 + q * 8];
#pragma unroll
    for (int nt = 0; nt < NTW; nt++) {
      short8 b = *(const short8*)(wbase + (size_t)(nt * 8 + ks) * 64 * 8);
#pragma unroll
      for (int mt = 0; mt < 4; mt++)
        acc[mt][nt] = __builtin_amdgcn_mfma_f32_16x16x32_bf16(a[mt], b, acc[mt][nt], 0, 0, 0);
    }
  }
  // epilogue: bf16 C tile -> LDS (padded) -> 16B coalesced global stores
  constexpr int NC = NTW * 64;    // 256 (gates) or 128 (candidate)
  constexpr int CST = NC + 8;     // LDS row stride in shorts
  __syncthreads();                // done reading As
#pragma unroll
  for (int mt = 0; mt < 4; mt++)
#pragma unroll
    for (int nt = 0; nt < NTW; nt++) {
      int col = (wv * NTW + nt) * 16 + m;
#pragma unroll
      for (int i = 0; i < 4; i++)
        As[(mt * 16 + q * 4 + i) * CST + col] = f2bf(acc[mt][nt][i]);
    }
  __syncthreads();
  constexpr int CPR = NC / 8;     // 16B chunks per row
  for (int c = tid; c < 64 * CPR; c += 256) {
    int row = c / CPR, cc = c % CPR;
    uint4 v = *(const uint4*)&As[row * CST + cc * 8];
    int col = cc * 8;
    unsigned short* op = (col < 128) ? outR : outU;
    *(uint4*)&op[(size_t)(rowBase + row) * 128 + (col & 127)] = v;
  }
}

// ---------------- gates aggregation: r|u halves, uint4 gathers, 2 nodes/block ----------------
// grid (NN/2, 2): y=0 -> r half (writes rh=r*h), y=1 -> u half (writes u).
// Thread map: sub=node-in-block, bb=batch, fh*8 = feature offset. Per edge, the
// 128 threads of one node read 8 rows x 256B = 2KB contiguous via uint4.

__global__ __launch_bounds__(256) void scatter_gates_kernel(
    const unsigned short* __restrict__ GR, const unsigned short* __restrict__ GU,
    const int* __restrict__ offs, const int* __restrict__ csr_src,
    const float* __restrict__ csr_w, const float* __restrict__ dis,
    const float* __restrict__ bRU, const unsigned short* __restrict__ h,
    unsigned short* __restrict__ rh, unsigned short* __restrict__ u) {
  int half = blockIdx.y;
  int tid = threadIdx.x;
  int sub = tid >> 7;              // node in block 0..1
  int rest = tid & 127;
  int bb = rest >> 4;              // batch 0..7
  int fo = (rest & 15) << 3;       // feature offset, 8 feats
  int n = blockIdx.x * 2 + sub;
  const unsigned short* G = half ? GU : GR;
  float sn = dis[n]; sn *= sn;
  size_t rowSelf = (size_t)(n << 3) + bb;
  uint4 gv = *(const uint4*)&G[rowSelf * 128 + fo];
  float a0 = sn * bflo(gv.x), a1 = sn * bfhi(gv.x);
  float a2 = sn * bflo(gv.y), a3 = sn * bfhi(gv.y);
  float a4 = sn * bflo(gv.z), a5 = sn * bfhi(gv.z);
  float a6 = sn * bflo(gv.w), a7 = sn * bfhi(gv.w);
  int e0 = offs[n], e1 = offs[n + 1];
  int e = e0;
  for (; e + 1 < e1; e += 2) {
    int s0 = csr_src[e], s1 = csr_src[e + 1];
    float w0 = csr_w[e], w1 = csr_w[e + 1];
    uint4 ga = *(const uint4*)&G[(((size_t)s0 << 3) + bb) * 128 + fo];
    uint4 gb = *(const uint4*)&G[(((size_t)s1 << 3) + bb) * 128 + fo];
    a0 += w0 * bflo(ga.x); a1 += w0 * bfhi(ga.x);
    a2 += w0 * bflo(ga.y); a3 += w0 * bfhi(ga.y);
    a4 += w0 * bflo(ga.z); a5 += w0 * bfhi(ga.z);
    a6 += w0 * bflo(ga.w); a7 += w0 * bfhi(ga.w);
    a0 += w1 * bflo(gb.x); a1 += w1 * bfhi(gb.x);
    a2 += w1 * bflo(gb.y); a3 += w1 * bfhi(gb.y);
    a4 += w1 * bflo(gb.z); a5 += w1 * bfhi(gb.z);
    a6 += w1 * bflo(gb.w); a7 += w1 * bfhi(gb.w);
  }
  if (e < e1) {
    int s0 = csr_src[e];
    float w0 = csr_w[e];
    uint4 ga = *(const uint4*)&G[(((size_t)s0 << 3) + bb) * 128 + fo];
    a0 += w0 * bflo(ga.x); a1 += w0 * bfhi(ga.x);
    a2 += w0 * bflo(ga.y); a3 += w0 * bfhi(ga.y);
    a4 += w0 * bflo(ga.z); a5 += w0 * bfhi(ga.z);
    a6 += w0 * bflo(ga.w); a7 += w0 * bfhi(ga.w);
  }
  const float* bias = bRU + half * 128 + fo;
  float v0 = 1.0f / (1.0f + __expf(-(a0 + bias[0])));
  float v1 = 1.0f / (1.0f + __expf(-(a1 + bias[1])));
  float v2 = 1.0f / (1.0f + __expf(-(a2 + bias[2])));
  float v3 = 1.0f / (1.0f + __expf(-(a3 + bias[3])));
  float v4 = 1.0f / (1.0f + __expf(-(a4 + bias[4])));
  float v5 = 1.0f / (1.0f + __expf(-(a5 + bias[5])));
  float v6 = 1.0f / (1.0f + __expf(-(a6 + bias[6])));
  float v7 = 1.0f / (1.0f + __expf(-(a7 + bias[7])));
  if (half == 0) {
    uint4 hv = *(const uint4*)&h[rowSelf * 128 + fo];
    v0 *= bflo(hv.x); v1 *= bfhi(hv.x); v2 *= bflo(hv.y); v3 *= bfhi(hv.y);
    v4 *= bflo(hv.z); v5 *= bfhi(hv.z); v6 *= bflo(hv.w); v7 *= bfhi(hv.w);
    uint4 o;
    o.x = (unsigned)f2bf(v0) | ((unsigned)f2bf(v1) << 16);
    o.y = (unsigned)f2bf(v2) | ((unsigned)f2bf(v3) << 16);
    o.z = (unsigned)f2bf(v4) | ((unsigned)f2bf(v5) << 16);
    o.w = (unsigned)f2bf(v6) | ((unsigned)f2bf(v7) << 16);
    *(uint4*)&rh[rowSelf * 128 + fo] = o;
  } else {
    uint4 o;
    o.x = (unsigned)f2bf(v0) | ((unsigned)f2bf(v1) << 16);
    o.y = (unsigned)f2bf(v2) | ((unsigned)f2bf(v3) << 16);
    o.z = (unsigned)f2bf(v4) | ((unsigned)f2bf(v5) << 16);
    o.w = (unsigned)f2bf(v6) | ((unsigned)f2bf(v7) << 16);
    *(uint4*)&u[rowSelf * 128 + fo] = o;
  }
}

// ---------------- candidate aggregation + GRU update, uint4 gathers, 2 nodes/block ----------------

__global__ __launch_bounds__(256) void scatter_c_update_kernel(
    const unsigned short* __restrict__ Cp, const int* __restrict__ offs,
    const int* __restrict__ csr_src, const float* __restrict__ csr_w,
    const float* __restrict__ dis, const float* __restrict__ bC,
    const unsigned short* __restrict__ u, unsigned short* __restrict__ h) {
  int tid = threadIdx.x;
  int sub = tid >> 7;
  int rest = tid & 127;
  int bb = rest >> 4;
  int fo = (rest & 15) << 3;
  int n = blockIdx.x * 2 + sub;
  float sn = dis[n]; sn *= sn;
  size_t rowSelf = (size_t)(n << 3) + bb;
  uint4 gv = *(const uint4*)&Cp[rowSelf * 128 + fo];
  float a0 = sn * bflo(gv.x), a1 = sn * bfhi(gv.x);
  float a2 = sn * bflo(gv.y), a3 = sn * bfhi(gv.y);
  float a4 = sn * bflo(gv.z), a5 = sn * bfhi(gv.z);
  float a6 = sn * bflo(gv.w), a7 = sn * bfhi(gv.w);
  int e0 = offs[n], e1 = offs[n + 1];
  int e = e0;
  for (; e + 1 < e1; e += 2) {
    int s0 = csr_src[e], s1 = csr_src[e + 1];
    float w0 = csr_w[e], w1 = csr_w[e + 1];
    uint4 ga = *(const uint4*)&Cp[(((size_t)s0 << 3) + bb) * 128 + fo];
    uint4 gb = *(const uint4*)&Cp[(((size_t)s1 << 3) + bb) * 128 + fo];
    a0 += w0 * bflo(ga.x); a1 += w0 * bfhi(ga.x);
    a2 += w0 * bflo(ga.y); a3 += w0 * bfhi(ga.y);
    a4 += w0 * bflo(ga.z); a5 += w0 * bfhi(ga.z);
    a6 += w0 * bflo(ga.w); a7 += w0 * bfhi(ga.w);
    a0 += w1 * bflo(gb.x); a1 += w1 * bfhi(gb.x);
    a2 += w1 * bflo(gb.y); a3 += w1 * bfhi(gb.y);
    a4 += w1 * bflo(gb.z); a5 += w1 * bfhi(gb.z);
    a6 += w1 * bflo(gb.w); a7 += w1 * bfhi(gb.w);
  }
  if (e < e1) {
    int s0 = csr_src[e];
    float w0 = csr_w[e];
    uint4 ga = *(const uint4*)&Cp[(((size_t)s0 << 3) + bb) * 128 + fo];
    a0 += w0 * bflo(ga.x); a1 += w0 * bfhi(ga.x);
    a2 += w0 * bflo(ga.y); a3 += w0 * bfhi(ga.y);
    a4 += w0 * bflo(ga.z); a5 += w0 * bfhi(ga.z);
    a6 += w0 * bflo(ga.w); a7 += w0 * bfhi(ga.w);
  }
  const float* bp = bC + fo;
  float c0 = 1.0f - 2.0f / (__expf(2.0f * (a0 + bp[0])) + 1.0f);
  float c1 = 1.0f - 2.0f / (__expf(2.0f * (a1 + bp[1])) + 1.0f);
  float c2 = 1.0f - 2.0f / (__expf(2.0f * (a2 + bp[2])) + 1.0f);
  float c3 = 1.0f - 2.0f / (__expf(2.0f * (a3 + bp[3])) + 1.0f);
  float c4 = 1.0f - 2.0f / (__expf(2.0f * (a4 + bp[4])) + 1.0f);
  float c5 = 1.0f - 2.0f / (__expf(2.0f * (a5 + bp[5])) + 1.0f);
  float c6 = 1.0f - 2.0f / (__expf(2.0f * (a6 + bp[6])) + 1.0f);
  float c7 = 1.0f - 2.0f / (__expf(2.0f * (a7 + bp[7])) + 1.0f);
  uint4 uv = *(const uint4*)&u[rowSelf * 128 + fo];
  uint4 hv = *(const uint4*)&h[rowSelf * 128 + fo];
  float u0 = bflo(uv.x), u1 = bfhi(uv.x), u2 = bflo(uv.y), u3 = bfhi(uv.y);
  float u4 = bflo(uv.z), u5 = bfhi(uv.z), u6 = bflo(uv.w), u7 = bfhi(uv.w);
  float h0 = bflo(hv.x), h1 = bfhi(hv.x), h2 = bflo(hv.y), h3 = bfhi(hv.y);
  float h4 = bflo(hv.z), h5 = bfhi(hv.z), h6 = bflo(hv.w), h7 = bfhi(hv.w);
  float n0 = u0 * h0 + (1.0f - u0) * c0;
  float n1 = u1 * h1 + (1.0f - u1) * c1;
  float n2 = u2 * h2 + (1.0f - u2) * c2;
  float n3 = u3 * h3 + (1.0f - u3) * c3;
  float n4 = u4 * h4 + (1.0f - u4) * c4;
  float n5 = u5 * h5 + (1.0f - u5) * c5;
  float n6 = u6 * h6 + (1.0f - u6) * c6;
  float n7 = u7 * h7 + (1.0f - u7) * c7;
  uint4 o;
  o.x = (unsigned)f2bf(n0) | ((unsigned)f2bf(n1) << 16);
  o.y = (unsigned)f2bf(n2) | ((unsigned)f2bf(n3) << 16);
  o.z = (unsigned)f2bf(n4) | ((unsigned)f2bf(n5) << 16);
  o.w = (unsigned)f2bf(n6) | ((unsigned)f2bf(n7) << 16);
  *(uint4*)&h[rowSelf * 128 + fo] = o;
}

// ---------------- BatchNorm stats ----------------

__global__ __launch_bounds__(256) void bn_stats_kernel(const unsigned short* __restrict__ h,
                                                       float* __restrict__ sums) {
  __shared__ float ls[512];
  int tid = threadIdx.x;
  float s = 0.f, sq = 0.f;
  for (size_t idx = (size_t)blockIdx.x * 256 + tid; idx < (size_t)TOTAL * HH;
       idx += (size_t)gridDim.x * 256) {
    float v = bf2f(h[idx]);
    s += v; sq += v * v;
  }
  ls[tid] = s; ls[256 + tid] = sq;
  __syncthreads();
  if (tid < 128) {
    atomicAdd(&sums[tid], ls[tid] + ls[tid + 128]);
    atomicAdd(&sums[128 + tid], ls[256 + tid] + ls[256 + tid + 128]);
  }
}

// ---------------- fused BN -> relu -> lin_out -> log_softmax ----------------

__global__ __launch_bounds__(256) void final_kernel(const unsigned short* __restrict__ h,
                                                    const float* __restrict__ sums,
                                                    const float* __restrict__ gamma,
                                                    const float* __restrict__ beta,
                                                    const float* __restrict__ Wout,
                                                    const float* __restrict__ bout,
                                                    float* __restrict__ out) {
  int wid = threadIdx.x >> 6, lane = threadIdx.x & 63;
  int row = blockIdx.x * 4 + wid; // node-row (n*8+bb order)
  if (row >= TOTAL) return;
  const float inv = 1.0f / (float)TOTAL;
  float p0 = 0.f, p1 = 0.f, p2 = 0.f, p3 = 0.f;
#pragma unroll
  for (int jj = 0; jj < 2; jj++) {
    int j = lane + jj * 64;
    float mean = sums[j] * inv;
    float var = sums[128 + j] * inv - mean * mean;
    float hn = (bf2f(h[(size_t)row * HH + j]) - mean) * rsqrtf(var + 1e-5f) * gamma[j] + beta[j];
    hn = fmaxf(hn, 0.0f);
    p0 += hn * Wout[j * 4 + 0];
    p1 += hn * Wout[j * 4 + 1];
    p2 += hn * Wout[j * 4 + 2];
    p3 += hn * Wout[j * 4 + 3];
  }
  for (int off = 32; off; off >>= 1) {
    p0 += __shfl_down(p0, off);
    p1 += __shfl_down(p1, off);
    p2 += __shfl_down(p2, off);
    p3 += __shfl_down(p3, off);
  }
  if (lane == 0) {
    p0 += bout[0]; p1 += bout[1]; p2 += bout[2]; p3 += bout[3];
    float m = fmaxf(fmaxf(p0, p1), fmaxf(p2, p3));
    float e = __expf(p0 - m) + __expf(p1 - m) + __expf(p2 - m) + __expf(p3 - m);
    float lse = m + __logf(e);
    int bb = row & 7, n = row >> 3;
    float* o = out + ((size_t)bb * NN + n) * 4;
    o[0] = p0 - lse; o[1] = p1 - lse; o[2] = p2 - lse; o[3] = p3 - lse;
  }
}

// ---------------- launcher ----------------

extern "C" void kernel_launch(void* const* d_in, const int* in_sizes, int n_in,
                              void* d_out, int out_size, void* d_ws, size_t ws_size,
                              hipStream_t stream) {
  const float* x_seq = (const float*)d_in[0];
  const int* ei      = (const int*)d_in[1];
  const float* ew    = (const float*)d_in[2];
  const float* Win   = (const float*)d_in[3];
  const float* bin   = (const float*)d_in[4];
  const float* convW = (const float*)d_in[5];
  const float* convB = (const float*)d_in[6];
  const float* gamma = (const float*)d_in[7];
  const float* beta  = (const float*)d_in[8];
  const float* Wout  = (const float*)d_in[9];
  const float* bout  = (const float*)d_in[10];
  float* out = (float*)d_out;

  char* ws = (char*)d_ws;
  size_t off = 0;
  auto alloc = [&](size_t bytes) {
    void* p = ws + off;
    off += (bytes + 1023) & ~(size_t)1023;
    return p;
  };
  float* deg     = (float*)alloc(NN * 4);
  float* dis     = (float*)alloc(NN * 4);
  int*   cnt     = (int*)alloc(NN * 4);
  int*   offs    = (int*)alloc((NN + 1) * 4);
  int*   cursor  = (int*)alloc(NN * 4);
  int*   csr_src = (int*)alloc(EE * 4);
  float* csr_w   = (float*)alloc(EE * 4);
  float* sums    = (float*)alloc(256 * 4);
  unsigned short* Wp = (unsigned short*)alloc(6 * 32768 * 2);  // packed conv weights
  const size_t NH = (size_t)TOTAL * HH; // 5,120,000
  unsigned short* h0 = (unsigned short*)alloc(NH * 2);
  unsigned short* h1 = (unsigned short*)alloc(NH * 2);
  unsigned short* xt = (unsigned short*)alloc(NH * 2);
  unsigned short* rh = (unsigned short*)alloc(NH * 2);
  unsigned short* ub = (unsigned short*)alloc(NH * 2);
  unsigned short* GR = (unsigned short*)alloc(NH * 2);
  unsigned short* GU = (unsigned short*)alloc(NH * 2);
  unsigned short* Cpre = GR;  // candidate pre-scatter reuses GR

  hipMemsetAsync(deg, 0, NN * 4, stream);
  hipMemsetAsync(cnt, 0, NN * 4, stream);
  hipMemsetAsync(cursor, 0, NN * 4, stream);
  hipMemsetAsync(sums, 0, 256 * 4, stream);
  hipMemsetAsync(h0, 0, NH * 2, stream);
  hipMemsetAsync(h1, 0, NH * 2, stream);

  deg_cnt_kernel<<<(EE + 255) / 256, 256, 0, stream>>>(ei, ew, deg, cnt);
  dis_kernel<<<(NN + 255) / 256, 256, 0, stream>>>(deg, dis);
  scan_kernel<<<1, 256, 0, stream>>>(cnt, offs);
  fill_csr_kernel<<<(EE + 255) / 256, 256, 0, stream>>>(ei, ew, dis, offs, cursor, csr_src, csr_w);
  prepack_kernel<<<24576 / 256, 256, 0, stream>>>(convW, Wp);

  for (int t = 0; t < SS; t++) {
    lin_in_kernel<<<TOTAL * 16 / 256, 256, 0, stream>>>(x_seq, Win, bin, xt, t);
    for (int l = 0; l < 2; l++) {
      const unsigned short* xin = (l == 0) ? xt : h0;
      unsigned short* h = (l == 0) ? h0 : h1;
      const unsigned short* Wg = Wp + (size_t)(l * 3) * 32768;
      const unsigned short* Wc = Wp + (size_t)(l * 3 + 2) * 32768;
      const float* bRU = convB + (size_t)l * 3 * HH;
      const float* bC  = bRU + 2 * HH;
      gemm_mfma<4><<<TOTAL / 64, 256, 0, stream>>>(xin, h, Wg, GR, GU);
      scatter_gates_kernel<<<dim3(NN / 2, 2), 256, 0, stream>>>(GR, GU, offs, csr_src, csr_w,
                                                                dis, bRU, h, rh, ub);
      gemm_mfma<2><<<TOTAL / 64, 256, 0, stream>>>(xin, rh, Wc, Cpre, Cpre);
      scatter_c_update_kernel<<<NN / 2, 256, 0, stream>>>(Cpre, offs, csr_src, csr_w,
                                                          dis, bC, ub, h);
    }
  }

  bn_stats_kernel<<<256, 256, 0, stream>>>(h1, sums);
  final_kernel<<<TOTAL / 4, 256, 0, stream>>>(h1, sums, gamma, beta, Wout, bout, out);
}

// Round 9
// 1894.080 us; speedup vs baseline: 1.2617x; 1.0971x over previous
//
#include <hip/hip_runtime.h>
#include <cstdint>
#include <cstddef>

#define NN 5000     // nodes per batch block
#define EE 40000    // edges per batch block
#define BATCH 8
#define SS 12
#define FF 16
#define HH 128
#define TOTAL 40000 // BATCH*NN
#define CC 4

// Layout: per-row state arrays use row = n*8 + bb (batch-interleaved). Gather-only
// message matrices (gates r|u pre-scatter, candidate pre-scatter) are stored INT8
// with one fp32 scale per source node per matrix -> gather bytes halve vs bf16.

typedef __attribute__((ext_vector_type(8))) short short8;   // 8 bf16 (4 VGPRs)
typedef __attribute__((ext_vector_type(4))) float f32x4;    // 4 fp32

__device__ __forceinline__ unsigned short f2bf(float f) {
  union { float f; unsigned u; } v; v.f = f;
  unsigned r = v.u + 0x7fff + ((v.u >> 16) & 1);  // RTNE
  return (unsigned short)(r >> 16);
}
__device__ __forceinline__ float bf2f(unsigned short b) {
  union { unsigned u; float f; } v; v.u = ((unsigned)b) << 16;
  return v.f;
}
__device__ __forceinline__ float bflo(unsigned v) {
  union { unsigned u; float f; } x; x.u = v << 16; return x.f;
}
__device__ __forceinline__ float bfhi(unsigned v) {
  union { unsigned u; float f; } x; x.u = v & 0xffff0000u; return x.f;
}
// acc[0..15] += ws * (int8x16 from qv)
__device__ __forceinline__ void qfma16(float* acc, uint4 qv, float ws) {
  unsigned wd[4] = {qv.x, qv.y, qv.z, qv.w};
#pragma unroll
  for (int d = 0; d < 4; d++) {
#pragma unroll
    for (int k = 0; k < 4; k++) {
      int q = (int)((signed char)(wd[d] >> (8 * k)));
      acc[d * 4 + k] += ws * (float)q;
    }
  }
}

// ---------------- graph preprocessing (once per launch) ----------------

__global__ void deg_cnt_kernel(const int* __restrict__ ei, const float* __restrict__ ew,
                               float* __restrict__ deg, int* __restrict__ cnt) {
  int e = blockIdx.x * 256 + threadIdx.x;
  if (e < EE) {
    int col = ei[EE + e];
    atomicAdd(&deg[col], ew[e]);
    atomicAdd(&cnt[col], 1);
  }
}

__global__ void dis_kernel(const float* __restrict__ deg, float* __restrict__ dis) {
  int n = blockIdx.x * 256 + threadIdx.x;
  if (n < NN) dis[n] = rsqrtf(deg[n] + 1.0f);  // +1: self-loop weight
}

__global__ void scan_kernel(const int* __restrict__ cnt, int* __restrict__ offs) {
  __shared__ int part[256];
  const int CH = (NN + 255) / 256; // 20
  int tid = threadIdx.x;
  int base = tid * CH;
  int s = 0;
  for (int i = 0; i < CH; i++) { int idx = base + i; if (idx < NN) s += cnt[idx]; }
  part[tid] = s;
  __syncthreads();
  for (int off = 1; off < 256; off <<= 1) {
    int v = (tid >= off) ? part[tid - off] : 0;
    __syncthreads();
    part[tid] += v;
    __syncthreads();
  }
  int run = (tid == 0) ? 0 : part[tid - 1];
  for (int i = 0; i < CH; i++) {
    int idx = base + i;
    if (idx < NN) { offs[idx] = run; run += cnt[idx]; }
  }
  if (tid == 255) offs[NN] = run;
}

__global__ void fill_csr_kernel(const int* __restrict__ ei, const float* __restrict__ ew,
                                const float* __restrict__ dis, const int* __restrict__ offs,
                                int* __restrict__ cursor, int* __restrict__ csr_src,
                                float* __restrict__ csr_w) {
  int e = blockIdx.x * 256 + threadIdx.x;
  if (e < EE) {
    int row = ei[e], col = ei[EE + e];
    int pos = offs[col] + atomicAdd(&cursor[col], 1);
    csr_src[pos] = row;
    csr_w[pos] = dis[row] * ew[e] * dis[col];
  }
}

// ---------------- weight prepack: fp32 [k][n] -> bf16 MFMA b-frag order ----------------

__global__ void prepack_kernel(const float* __restrict__ convW, unsigned short* __restrict__ Wp) {
  int idx = blockIdx.x * 256 + threadIdx.x;  // 6*8*8*64 = 24576
  int lane = idx & 63;
  int ks = (idx >> 6) & 7;
  int nt = (idx >> 9) & 7;
  int g = idx >> 12;
  const float* W = convW + (size_t)g * 256 * 128;
  int n = nt * 16 + (lane & 15);
  int k0 = ks * 32 + (lane >> 4) * 8;
  unsigned short v[8];
#pragma unroll
  for (int j = 0; j < 8; j++) v[j] = f2bf(W[(size_t)(k0 + j) * 128 + n]);
  *(uint4*)(Wp + (size_t)idx * 8) = *(const uint4*)v;
}

// ---------------- lin_in: xt = relu(x_t @ Win + bin), bf16 out, row = n*8+bb ----------------

__global__ __launch_bounds__(256) void lin_in_kernel(const float* __restrict__ x_seq,
                                                     const float* __restrict__ W,
                                                     const float* __restrict__ b,
                                                     unsigned short* __restrict__ xt, int t) {
  int idx = blockIdx.x * 256 + threadIdx.x;   // over TOTAL*16
  int row = idx >> 4, fh = idx & 15;          // feats 8fh..8fh+7
  int n = row >> 3, bb = row & 7;
  const float* xp = x_seq + (((size_t)bb * SS + t) * NN + n) * FF;
  float4 a0 = *(const float4*)&b[fh * 8];
  float4 a1 = *(const float4*)&b[fh * 8 + 4];
#pragma unroll
  for (int ff = 0; ff < FF; ff++) {
    float xv = xp[ff];
    float4 w0 = *(const float4*)&W[ff * HH + fh * 8];
    float4 w1 = *(const float4*)&W[ff * HH + fh * 8 + 4];
    a0.x += xv * w0.x; a0.y += xv * w0.y; a0.z += xv * w0.z; a0.w += xv * w0.w;
    a1.x += xv * w1.x; a1.y += xv * w1.y; a1.z += xv * w1.z; a1.w += xv * w1.w;
  }
  uint4 o;
  o.x = (unsigned)f2bf(fmaxf(a0.x, 0.f)) | ((unsigned)f2bf(fmaxf(a0.y, 0.f)) << 16);
  o.y = (unsigned)f2bf(fmaxf(a0.z, 0.f)) | ((unsigned)f2bf(fmaxf(a0.w, 0.f)) << 16);
  o.z = (unsigned)f2bf(fmaxf(a1.x, 0.f)) | ((unsigned)f2bf(fmaxf(a1.y, 0.f)) << 16);
  o.w = (unsigned)f2bf(fmaxf(a1.z, 0.f)) | ((unsigned)f2bf(fmaxf(a1.w, 0.f)) << 16);
  *(uint4*)&xt[(size_t)row * 128 + fh * 8] = o;
}

// ---------------- bf16 MFMA GEMM -> int8-quantized output + per-node scales ----------------
// C = concat(A1,A2) @ Wpacked. C tile (64 x NC) staged bf16 in LDS, then per source
// node-group (8 rows) x half: scale = max|.|/127, output int8 rows of 128 bytes.

template <int NTW, int HALVES>
__global__ __launch_bounds__(256) void gemm_mfma_q(const unsigned short* __restrict__ A1,
                                                   const unsigned short* __restrict__ A2,
                                                   const unsigned short* __restrict__ Wp,
                                                   signed char* __restrict__ qA,
                                                   signed char* __restrict__ qB,
                                                   float* __restrict__ sA,
                                                   float* __restrict__ sB) {
  __shared__ unsigned short As[64 * 264];  // A staging; reused for C epilogue
  __shared__ float sInv[16];
  int rowBase = blockIdx.x * 64;
  int tid = threadIdx.x;
  for (int c = tid; c < 2048; c += 256) {
    int row = c >> 5; int rest = c & 31; int half = rest >> 4; int sub = rest & 15;
    const unsigned short* src = (half ? A2 : A1) + ((size_t)(rowBase + row) * 128 + sub * 8);
    *(uint4*)&As[row * 264 + half * 128 + sub * 8] = *(const uint4*)src;
  }
  __syncthreads();
  int wv = tid >> 6, lane = tid & 63;
  int m = lane & 15, q = lane >> 4;
  f32x4 acc[4][NTW];
#pragma unroll
  for (int i = 0; i < 4; i++)
#pragma unroll
    for (int j = 0; j < NTW; j++) acc[i][j] = (f32x4)(0.0f);
  const unsigned short* wbase = Wp + ((size_t)(wv * NTW) * 8 * 64 + lane) * 8;
#pragma unroll
  for (int ks = 0; ks < 8; ks++) {
    short8 a[4];
#pragma unroll
    for (int mt = 0; mt < 4; mt++)
      a[mt] = *(const short8*)&As[(mt * 16 + m) * 264 + ks * 32 + q * 8];
#pragma unroll
    for (int nt = 0; nt < NTW; nt++) {
      short8 b = *(const short8*)(wbase + (size_t)(nt * 8 + ks) * 64 * 8);
#pragma unroll
      for (int mt = 0; mt < 4; mt++)
        acc[mt][nt] = __builtin_amdgcn_mfma_f32_16x16x32_bf16(a[mt], b, acc[mt][nt], 0, 0, 0);
    }
  }
  constexpr int NC = NTW * 64;    // 256 (gates) or 128 (candidate)
  constexpr int CST = NC + 8;     // LDS row stride in shorts
  __syncthreads();                // done reading As
#pragma unroll
  for (int mt = 0; mt < 4; mt++)
#pragma unroll
    for (int nt = 0; nt < NTW; nt++) {
      int col = (wv * NTW + nt) * 16 + m;
#pragma unroll
      for (int i = 0; i < 4; i++)
        As[(mt * 16 + q * 4 + i) * CST + col] = f2bf(acc[mt][nt][i]);
    }
  __syncthreads();
  // per (node, half) max over 8 rows x 128 cols
  {
    constexpr int G = 8 * HALVES;     // groups per tile
    constexpr int TPG = 256 / G;      // 16 or 32 threads per group
    constexpr int CPT = 128 / TPG;    // 8 or 4 cols per thread
    int g = tid / TPG, j = tid % TPG;
    int node = g / HALVES;
    int half = g % HALVES;
    int c0 = half * 128 + j * CPT;
    float mx = 0.f;
#pragma unroll
    for (int r = 0; r < 8; r++) {
      const unsigned short* rp = &As[(node * 8 + r) * CST + c0];
#pragma unroll
      for (int k = 0; k < CPT; k++) mx = fmaxf(mx, fabsf(bf2f(rp[k])));
    }
#pragma unroll
    for (int off = TPG / 2; off; off >>= 1)
      mx = fmaxf(mx, __shfl_down(mx, off, TPG));
    if (j == 0) {
      sInv[g] = (mx > 0.f) ? (127.0f / mx) : 0.f;
      int gn = (rowBase >> 3) + node;
      float sc = mx * (1.0f / 127.0f);
      if (HALVES == 2) { if (half == 0) sA[gn] = sc; else sB[gn] = sc; }
      else sA[gn] = sc;
    }
  }
  __syncthreads();
  // quantize + 16B stores
  constexpr int CPQ = NC / 16;    // 16B chunks per row
  for (int c = tid; c < 64 * CPQ; c += 256) {
    int row = c / CPQ, cc = c % CPQ;
    int node = row >> 3;
    int half = (HALVES == 2) ? (cc >> 3) : 0;
    float inv = sInv[node * HALVES + half];
    const unsigned short* p = &As[row * CST + cc * 16];
    unsigned ow[4];
#pragma unroll
    for (int d = 0; d < 4; d++) {
      unsigned w = 0;
#pragma unroll
      for (int k = 0; k < 4; k++) {
        int qv = __float2int_rn(bf2f(p[d * 4 + k]) * inv);
        w |= ((unsigned)(qv & 255)) << (8 * k);
      }
      ow[d] = w;
    }
    signed char* dst = (half ? qB : qA) + (size_t)(rowBase + row) * 128 + (cc & 7) * 16;
    uint4 v; v.x = ow[0]; v.y = ow[1]; v.z = ow[2]; v.w = ow[3];
    *(uint4*)dst = v;
  }
}

// ---------------- gates aggregation over int8 messages ----------------
// grid NN/2, block = 4 waves: wave -> (node = bid*2 + wv>>1, half = wv&1).
// lane -> (bb = lane>>3, 16 feats at (lane&7)*16). Per edge a wave reads 8 rows
// x 128B = 1KB contiguous int8.

__global__ __launch_bounds__(256) void scatter_gates_q(
    const signed char* __restrict__ GqR, const signed char* __restrict__ GqU,
    const float* __restrict__ sR, const float* __restrict__ sU,
    const int* __restrict__ offs, const int* __restrict__ csr_src,
    const float* __restrict__ csr_w, const float* __restrict__ dis,
    const float* __restrict__ bRU, const unsigned short* __restrict__ h,
    unsigned short* __restrict__ rh, unsigned short* __restrict__ u) {
  int tid = threadIdx.x;
  int wv = tid >> 6, lane = tid & 63;
  int n = blockIdx.x * 2 + (wv >> 1);
  int half = wv & 1;
  int bb = lane >> 3;
  int fo = (lane & 7) << 4;      // 16 feats
  const signed char* Gq = half ? GqU : GqR;
  const float* sc = half ? sU : sR;
  float acc[16];
  float sn = dis[n]; sn *= sn;
  size_t rowSelf = (size_t)(n << 3) + bb;
  {
    float ws = sn * sc[n];
    uint4 qv = *(const uint4*)&Gq[rowSelf * 128 + fo];
#pragma unroll
    for (int k = 0; k < 16; k++) acc[k] = 0.f;
    qfma16(acc, qv, ws);
  }
  int e0 = offs[n], e1 = offs[n + 1];
  int e = e0;
  for (; e + 1 < e1; e += 2) {
    int s0 = csr_src[e], s1 = csr_src[e + 1];
    float w0 = csr_w[e] * sc[s0];
    float w1 = csr_w[e + 1] * sc[s1];
    uint4 qa = *(const uint4*)&Gq[(((size_t)s0 << 3) + bb) * 128 + fo];
    uint4 qb = *(const uint4*)&Gq[(((size_t)s1 << 3) + bb) * 128 + fo];
    qfma16(acc, qa, w0);
    qfma16(acc, qb, w1);
  }
  if (e < e1) {
    int s0 = csr_src[e];
    float w0 = csr_w[e] * sc[s0];
    uint4 qa = *(const uint4*)&Gq[(((size_t)s0 << 3) + bb) * 128 + fo];
    qfma16(acc, qa, w0);
  }
  const float* bias = bRU + half * 128 + fo;
  float v[16];
#pragma unroll
  for (int k = 0; k < 16; k++)
    v[k] = 1.0f / (1.0f + __expf(-(acc[k] + bias[k])));
  if (half == 0) {
    uint4 h0 = *(const uint4*)&h[rowSelf * 128 + fo];
    uint4 h1 = *(const uint4*)&h[rowSelf * 128 + fo + 8];
    float hv[16];
    hv[0] = bflo(h0.x); hv[1] = bfhi(h0.x); hv[2] = bflo(h0.y); hv[3] = bfhi(h0.y);
    hv[4] = bflo(h0.z); hv[5] = bfhi(h0.z); hv[6] = bflo(h0.w); hv[7] = bfhi(h0.w);
    hv[8] = bflo(h1.x); hv[9] = bfhi(h1.x); hv[10] = bflo(h1.y); hv[11] = bfhi(h1.y);
    hv[12] = bflo(h1.z); hv[13] = bfhi(h1.z); hv[14] = bflo(h1.w); hv[15] = bfhi(h1.w);
    unsigned ow[8];
#pragma unroll
    for (int d = 0; d < 8; d++)
      ow[d] = (unsigned)f2bf(v[2 * d] * hv[2 * d]) |
              ((unsigned)f2bf(v[2 * d + 1] * hv[2 * d + 1]) << 16);
    uint4 o0; o0.x = ow[0]; o0.y = ow[1]; o0.z = ow[2]; o0.w = ow[3];
    uint4 o1; o1.x = ow[4]; o1.y = ow[5]; o1.z = ow[6]; o1.w = ow[7];
    *(uint4*)&rh[rowSelf * 128 + fo] = o0;
    *(uint4*)&rh[rowSelf * 128 + fo + 8] = o1;
  } else {
    unsigned ow[8];
#pragma unroll
    for (int d = 0; d < 8; d++)
      ow[d] = (unsigned)f2bf(v[2 * d]) | ((unsigned)f2bf(v[2 * d + 1]) << 16);
    uint4 o0; o0.x = ow[0]; o0.y = ow[1]; o0.z = ow[2]; o0.w = ow[3];
    uint4 o1; o1.x = ow[4]; o1.y = ow[5]; o1.z = ow[6]; o1.w = ow[7];
    *(uint4*)&u[rowSelf * 128 + fo] = o0;
    *(uint4*)&u[rowSelf * 128 + fo + 8] = o1;
  }
}

// ---------------- candidate aggregation + GRU update over int8 messages ----------------
// grid NN/4, wave = one node.

__global__ __launch_bounds__(256) void scatter_c_update_q(
    const signed char* __restrict__ Cq, const float* __restrict__ sC,
    const int* __restrict__ offs, const int* __restrict__ csr_src,
    const float* __restrict__ csr_w, const float* __restrict__ dis,
    const float* __restrict__ bC, const unsigned short* __restrict__ u,
    unsigned short* __restrict__ h) {
  int tid = threadIdx.x;
  int wv = tid >> 6, lane = tid & 63;
  int n = blockIdx.x * 4 + wv;
  int bb = lane >> 3;
  int fo = (lane & 7) << 4;
  float acc[16];
  float sn = dis[n]; sn *= sn;
  size_t rowSelf = (size_t)(n << 3) + bb;
  {
    float ws = sn * sC[n];
    uint4 qv = *(const uint4*)&Cq[rowSelf * 128 + fo];
#pragma unroll
    for (int k = 0; k < 16; k++) acc[k] = 0.f;
    qfma16(acc, qv, ws);
  }
  int e0 = offs[n], e1 = offs[n + 1];
  int e = e0;
  for (; e + 1 < e1; e += 2) {
    int s0 = csr_src[e], s1 = csr_src[e + 1];
    float w0 = csr_w[e] * sC[s0];
    float w1 = csr_w[e + 1] * sC[s1];
    uint4 qa = *(const uint4*)&Cq[(((size_t)s0 << 3) + bb) * 128 + fo];
    uint4 qb = *(const uint4*)&Cq[(((size_t)s1 << 3) + bb) * 128 + fo];
    qfma16(acc, qa, w0);
    qfma16(acc, qb, w1);
  }
  if (e < e1) {
    int s0 = csr_src[e];
    float w0 = csr_w[e] * sC[s0];
    uint4 qa = *(const uint4*)&Cq[(((size_t)s0 << 3) + bb) * 128 + fo];
    qfma16(acc, qa, w0);
  }
  uint4 u0 = *(const uint4*)&u[rowSelf * 128 + fo];
  uint4 u1 = *(const uint4*)&u[rowSelf * 128 + fo + 8];
  uint4 h0 = *(const uint4*)&h[rowSelf * 128 + fo];
  uint4 h1 = *(const uint4*)&h[rowSelf * 128 + fo + 8];
  float uv[16], hv[16];
  uv[0] = bflo(u0.x); uv[1] = bfhi(u0.x); uv[2] = bflo(u0.y); uv[3] = bfhi(u0.y);
  uv[4] = bflo(u0.z); uv[5] = bfhi(u0.z); uv[6] = bflo(u0.w); uv[7] = bfhi(u0.w);
  uv[8] = bflo(u1.x); uv[9] = bfhi(u1.x); uv[10] = bflo(u1.y); uv[11] = bfhi(u1.y);
  uv[12] = bflo(u1.z); uv[13] = bfhi(u1.z); uv[14] = bflo(u1.w); uv[15] = bfhi(u1.w);
  hv[0] = bflo(h0.x); hv[1] = bfhi(h0.x); hv[2] = bflo(h0.y); hv[3] = bfhi(h0.y);
  hv[4] = bflo(h0.z); hv[5] = bfhi(h0.z); hv[6] = bflo(h0.w); hv[7] = bfhi(h0.w);
  hv[8] = bflo(h1.x); hv[9] = bfhi(h1.x); hv[10] = bflo(h1.y); hv[11] = bfhi(h1.y);
  hv[12] = bflo(h1.z); hv[13] = bfhi(h1.z); hv[14] = bflo(h1.w); hv[15] = bfhi(h1.w);
  const float* bp = bC + fo;
  float nv[16];
#pragma unroll
  for (int k = 0; k < 16; k++) {
    float val = acc[k] + bp[k];
    float c = 1.0f - 2.0f / (__expf(2.0f * val) + 1.0f);  // tanh
    nv[k] = uv[k] * hv[k] + (1.0f - uv[k]) * c;
  }
  unsigned ow[8];
#pragma unroll
  for (int d = 0; d < 8; d++)
    ow[d] = (unsigned)f2bf(nv[2 * d]) | ((unsigned)f2bf(nv[2 * d + 1]) << 16);
  uint4 o0; o0.x = ow[0]; o0.y = ow[1]; o0.z = ow[2]; o0.w = ow[3];
  uint4 o1; o1.x = ow[4]; o1.y = ow[5]; o1.z = ow[6]; o1.w = ow[7];
  *(uint4*)&h[rowSelf * 128 + fo] = o0;
  *(uint4*)&h[rowSelf * 128 + fo + 8] = o1;
}

// ---------------- BatchNorm stats ----------------

__global__ __launch_bounds__(256) void bn_stats_kernel(const unsigned short* __restrict__ h,
                                                       float* __restrict__ sums) {
  __shared__ float ls[512];
  int tid = threadIdx.x;
  float s = 0.f, sq = 0.f;
  for (size_t idx = (size_t)blockIdx.x * 256 + tid; idx < (size_t)TOTAL * HH;
       idx += (size_t)gridDim.x * 256) {
    float v = bf2f(h[idx]);
    s += v; sq += v * v;
  }
  ls[tid] = s; ls[256 + tid] = sq;
  __syncthreads();
  if (tid < 128) {
    atomicAdd(&sums[tid], ls[tid] + ls[tid + 128]);
    atomicAdd(&sums[128 + tid], ls[256 + tid] + ls[256 + tid + 128]);
  }
}

// ---------------- fused BN -> relu -> lin_out -> log_softmax ----------------

__global__ __launch_bounds__(256) void final_kernel(const unsigned short* __restrict__ h,
                                                    const float* __restrict__ sums,
                                                    const float* __restrict__ gamma,
                                                    const float* __restrict__ beta,
                                                    const float* __restrict__ Wout,
                                                    const float* __restrict__ bout,
                                                    float* __restrict__ out) {
  int wid = threadIdx.x >> 6, lane = threadIdx.x & 63;
  int row = blockIdx.x * 4 + wid; // node-row (n*8+bb order)
  if (row >= TOTAL) return;
  const float inv = 1.0f / (float)TOTAL;
  float p0 = 0.f, p1 = 0.f, p2 = 0.f, p3 = 0.f;
#pragma unroll
  for (int jj = 0; jj < 2; jj++) {
    int j = lane + jj * 64;
    float mean = sums[j] * inv;
    float var = sums[128 + j] * inv - mean * mean;
    float hn = (bf2f(h[(size_t)row * HH + j]) - mean) * rsqrtf(var + 1e-5f) * gamma[j] + beta[j];
    hn = fmaxf(hn, 0.0f);
    p0 += hn * Wout[j * 4 + 0];
    p1 += hn * Wout[j * 4 + 1];
    p2 += hn * Wout[j * 4 + 2];
    p3 += hn * Wout[j * 4 + 3];
  }
  for (int off = 32; off; off >>= 1) {
    p0 += __shfl_down(p0, off);
    p1 += __shfl_down(p1, off);
    p2 += __shfl_down(p2, off);
    p3 += __shfl_down(p3, off);
  }
  if (lane == 0) {
    p0 += bout[0]; p1 += bout[1]; p2 += bout[2]; p3 += bout[3];
    float m = fmaxf(fmaxf(p0, p1), fmaxf(p2, p3));
    float e = __expf(p0 - m) + __expf(p1 - m) + __expf(p2 - m) + __expf(p3 - m);
    float lse = m + __logf(e);
    int bb = row & 7, n = row >> 3;
    float* o = out + ((size_t)bb * NN + n) * 4;
    o[0] = p0 - lse; o[1] = p1 - lse; o[2] = p2 - lse; o[3] = p3 - lse;
  }
}

// ---------------- launcher ----------------

extern "C" void kernel_launch(void* const* d_in, const int* in_sizes, int n_in,
                              void* d_out, int out_size, void* d_ws, size_t ws_size,
                              hipStream_t stream) {
  const float* x_seq = (const float*)d_in[0];
  const int* ei      = (const int*)d_in[1];
  const float* ew    = (const float*)d_in[2];
  const float* Win   = (const float*)d_in[3];
  const float* bin   = (const float*)d_in[4];
  const float* convW = (const float*)d_in[5];
  const float* convB = (const float*)d_in[6];
  const float* gamma = (const float*)d_in[7];
  const float* beta  = (const float*)d_in[8];
  const float* Wout  = (const float*)d_in[9];
  const float* bout  = (const float*)d_in[10];
  float* out = (float*)d_out;

  char* ws = (char*)d_ws;
  size_t off = 0;
  auto alloc = [&](size_t bytes) {
    void* p = ws + off;
    off += (bytes + 1023) & ~(size_t)1023;
    return p;
  };
  float* deg     = (float*)alloc(NN * 4);
  float* dis     = (float*)alloc(NN * 4);
  int*   cnt     = (int*)alloc(NN * 4);
  int*   offs    = (int*)alloc((NN + 1) * 4);
  int*   cursor  = (int*)alloc(NN * 4);
  int*   csr_src = (int*)alloc(EE * 4);
  float* csr_w   = (float*)alloc(EE * 4);
  float* sums    = (float*)alloc(256 * 4);
  float* sR      = (float*)alloc(NN * 4);
  float* sU      = (float*)alloc(NN * 4);
  float* sC      = (float*)alloc(NN * 4);
  unsigned short* Wp = (unsigned short*)alloc(6 * 32768 * 2);  // packed conv weights
  const size_t NH = (size_t)TOTAL * HH; // 5,120,000
  unsigned short* h0 = (unsigned short*)alloc(NH * 2);
  unsigned short* h1 = (unsigned short*)alloc(NH * 2);
  unsigned short* xt = (unsigned short*)alloc(NH * 2);
  unsigned short* rh = (unsigned short*)alloc(NH * 2);
  unsigned short* ub = (unsigned short*)alloc(NH * 2);
  signed char* GqR = (signed char*)alloc(NH);   // int8 messages
  signed char* GqU = (signed char*)alloc(NH);
  signed char* Cq  = GqR;                       // candidate reuses GqR

  hipMemsetAsync(deg, 0, NN * 4, stream);
  hipMemsetAsync(cnt, 0, NN * 4, stream);
  hipMemsetAsync(cursor, 0, NN * 4, stream);
  hipMemsetAsync(sums, 0, 256 * 4, stream);
  hipMemsetAsync(h0, 0, NH * 2, stream);
  hipMemsetAsync(h1, 0, NH * 2, stream);

  deg_cnt_kernel<<<(EE + 255) / 256, 256, 0, stream>>>(ei, ew, deg, cnt);
  dis_kernel<<<(NN + 255) / 256, 256, 0, stream>>>(deg, dis);
  scan_kernel<<<1, 256, 0, stream>>>(cnt, offs);
  fill_csr_kernel<<<(EE + 255) / 256, 256, 0, stream>>>(ei, ew, dis, offs, cursor, csr_src, csr_w);
  prepack_kernel<<<24576 / 256, 256, 0, stream>>>(convW, Wp);

  for (int t = 0; t < SS; t++) {
    lin_in_kernel<<<TOTAL * 16 / 256, 256, 0, stream>>>(x_seq, Win, bin, xt, t);
    for (int l = 0; l < 2; l++) {
      const unsigned short* xin = (l == 0) ? xt : h0;
      unsigned short* h = (l == 0) ? h0 : h1;
      const unsigned short* Wg = Wp + (size_t)(l * 3) * 32768;
      const unsigned short* Wc = Wp + (size_t)(l * 3 + 2) * 32768;
      const float* bRU = convB + (size_t)l * 3 * HH;
      const float* bC  = bRU + 2 * HH;
      gemm_mfma_q<4, 2><<<TOTAL / 64, 256, 0, stream>>>(xin, h, Wg, GqR, GqU, sR, sU);
      scatter_gates_q<<<NN / 2, 256, 0, stream>>>(GqR, GqU, sR, sU, offs, csr_src, csr_w,
                                                  dis, bRU, h, rh, ub);
      gemm_mfma_q<2, 1><<<TOTAL / 64, 256, 0, stream>>>(xin, rh, Wc, Cq, Cq, sC, sC);
      scatter_c_update_q<<<NN / 4, 256, 0, stream>>>(Cq, sC, offs, csr_src, csr_w,
                                                     dis, bC, ub, h);
    }
  }

  bn_stats_kernel<<<256, 256, 0, stream>>>(h1, sums);
  final_kernel<<<TOTAL / 4, 256, 0, stream>>>(h1, sums, gamma, beta, Wout, bout, out);
}